// Round 1
// 412.160 us; speedup vs baseline: 1.0557x; 1.0557x over previous
//
#include <hip/hip_runtime.h>

#define HH 512
#define WW 512
#define NPIX (HH * WW)          // 262144
#define NIMG 16
#define KPTS 1024
#define NWORDS (NPIX / 64)      // 4096 u64 mask words per image

// ---------------------------------------------------------------------------
// Kernel 1: binarize + uniform LBP (P=8,R=1) — PURE BOOLEAN form.
// On a binary image the bilinear-threshold reduces exactly:
//   center=0 -> all 8 bits = 1 -> s=8 -> never masked  => maskbit needs b00
//   center=1 -> bit_k = AND of the nonzero-weight corners (even k: 1 nbr;
//               odd k: 4 corners). Rounding-independent: all-ones bilinear
//               sums to exactly 1.0 (1-fr exact for every r), any missing
//               corner subtracts >= 0.0858 >> ulp.
// Only the clamped 3x3 neighborhood is needed (9 loads, was 33).
// Edge cases r==0 / c==0: second row/col of the -A directions is index 1
// (= rp/cp), handled by the t2*/.c2 selects below.
// ---------------------------------------------------------------------------
__global__ void lbp_kernel(const float* __restrict__ mo,
                           const float* __restrict__ lb,
                           unsigned long long* __restrict__ maskbits) {
    int m = blockIdx.y;                    // image 0..15: even=pred, odd=mask
    int pix = blockIdx.x * blockDim.x + threadIdx.x;   // 0..262143
    int r = pix >> 9, c = pix & 511;
    int sample = m >> 1;
    const float* img = (m & 1) ? (lb + sample * NPIX) : (mo + sample * NPIX);
    float thr = (m & 1) ? 0.5f : 0.0f;     // sigmoid(x)>0.5 <=> x>0

    int rm = r - (r > 0), rp = r + (r < HH - 1);
    int cm = c - (c > 0), cp = c + (c < WW - 1);
    const float* rowm = img + rm * WW;
    const float* row0 = img + r  * WW;
    const float* rowp = img + rp * WW;

    bool bmm = rowm[cm] > thr, bm0 = rowm[c] > thr, bmp = rowm[cp] > thr;
    bool b0m = row0[cm] > thr, b00 = row0[c] > thr, b0p = row0[cp] > thr;
    bool bpm = rowp[cm] > thr, bp0 = rowp[c] > thr, bpp = rowp[cp] > thr;

    bool r0e = (r == 0), c0e = (c == 0);
    // dr=-A second row is min(rm+1,511): row r normally, row rp when r==0
    bool t2m = r0e ? bpm : b0m;    // B(row2, cm)
    bool t2c = r0e ? bp0 : b00;    // B(row2, c)
    bool t2p = r0e ? bpp : b0p;    // B(row2, cp)
    // dc=-A second col is min(cm+1,511): col c normally, col cp when c==0
    bool mc2 = c0e ? bmp : bm0;    // B(rm,  col2)
    bool tc2 = c0e ? t2p : t2c;    // B(row2,col2)
    bool zc2 = c0e ? b0p : b00;    // B(r,   col2)
    bool pc2 = c0e ? bpp : bp0;    // B(rp,  col2)

    unsigned bb =
        (b0p                     ?   1u : 0u)    // k=0: (r, c+1)
      | ((bm0 & bmp & t2c & t2p) ?   2u : 0u)    // k=1: rows(rm,row2) cols(c,cp)
      | (bm0                     ?   4u : 0u)    // k=2: (r-1, c)
      | ((bmm & mc2 & t2m & tc2) ?   8u : 0u)    // k=3: rows(rm,row2) cols(cm,col2)
      | (b0m                     ?  16u : 0u)    // k=4: (r, c-1)
      | ((b0m & zc2 & bpm & pc2) ?  32u : 0u)    // k=5: rows(r,rp) cols(cm,col2)
      | (bp0                     ?  64u : 0u)    // k=6: (r+1, c)
      | ((b0p & bp0 & bpp)       ? 128u : 0u);   // k=7: rows(r,rp) cols(c,cp)

    unsigned rol = ((bb << 1) | (bb >> 7)) & 0xFFu;
    int changes = __popc(bb ^ rol);
    int s = __popc(bb);
    bool maskbit = b00 && (changes <= 2) && (s < 5);   // lbp < THR(=5)

    unsigned long long w = __ballot(maskbit);
    if ((threadIdx.x & 63) == 0)
        maskbits[m * NWORDS + (pix >> 6)] = w;
}

// ---------------------------------------------------------------------------
// Kernel 2: stable row-major compaction to K=1024 packed points per image
// pts entry: (r<<16)|c ; zero-padded. Shfl scan + uniform early-exit once
// K points are found (random inputs -> chunk 0 already has ~2x K).
// ---------------------------------------------------------------------------
__global__ void select_kernel(const unsigned long long* __restrict__ maskbits,
                              unsigned* __restrict__ ptsG) {
    __shared__ unsigned swv[4];
    int m = blockIdx.x, tid = threadIdx.x;
    int lane = tid & 63, wid = tid >> 6;

    for (int i = tid; i < KPTS; i += 256) ptsG[m * KPTS + i] = 0u;
    __syncthreads();

    unsigned running = 0;
    for (int ch = 0; ch < 16; ch++) {
        int w = ch * 256 + tid;
        unsigned long long word = maskbits[m * NWORDS + w];
        unsigned cnt = (unsigned)__popcll(word);

        unsigned x = cnt;                    // intra-wave inclusive scan
#pragma unroll
        for (int d = 1; d < 64; d <<= 1) {
            unsigned y = (unsigned)__shfl_up((int)x, d, 64);
            x += (lane >= d) ? y : 0u;
        }
        if (lane == 63) swv[wid] = x;
        __syncthreads();
        unsigned woff = 0, total = 0;
#pragma unroll
        for (int ww = 0; ww < 4; ww++) {
            unsigned t = swv[ww];
            total += t;
            woff += (ww < wid) ? t : 0u;
        }
        unsigned rank = running + woff + x - cnt;   // exclusive prefix
        while (word) {
            int b = __builtin_ctzll(word);
            word &= word - 1;
            if (rank < (unsigned)KPTS) {
                unsigned p = (unsigned)(w * 64 + b);
                unsigned rr = p >> 9, cc = p & 511u;
                ptsG[m * KPTS + rank] = (rr << 16) | cc;
            }
            rank++;
        }
        running += total;
        if (running >= (unsigned)KPTS) break;   // uniform -> safe
        __syncthreads();   // protect swv before next chunk
    }
}

// ---------------------------------------------------------------------------
// Kernel 3 (phase 1): 4-WAVE Prim per image (was 1 wave — latency-bound at
// ~713 cyc/iter on a fully serial dependent chain). Keys are PARTITIONED
// (4 slots/wave = 256 nodes), points are REPLICATED per wave (p0..p15) so
// pj extraction (SEL16P + readlane) stays wave-local. Per iteration each
// wave DPP-reduces its partial min to lane63 (row_shr + row_bcast, no
// readlane tail), lane63 writes 4B to LDS, ONE __syncthreads (parity
// double-buffer makes a 2nd barrier unnecessary: the read is consumed
// before the reader can reach the next barrier, which fences the t+2
// overwrite), then every wave ds_read_b128-broadcasts the 4 wave-minima.
// Key values / idx tie-break / signed-min self-kill / edge encoding are
// bit-identical to the 1-wave version => identical extraction order.
// ---------------------------------------------------------------------------
typedef short v2s __attribute__((ext_vector_type(2)));
typedef unsigned u32x4 __attribute__((ext_vector_type(4)));

__device__ __forceinline__ int dist2_packed(unsigned a, unsigned b) {
#if __has_builtin(__builtin_amdgcn_sdot2)
    v2s d = __builtin_bit_cast(v2s, a) - __builtin_bit_cast(v2s, b);
    return __builtin_amdgcn_sdot2(d, d, 0, false);
#else
    int dr = (int)(a >> 16) - (int)(b >> 16);
    int dc = (int)(a & 0xFFFFu) - (int)(b & 0xFFFFu);
    return __mul24(dr, dr) + __mul24(dc, dc);
#endif
}

template <int CTRL>
__device__ __forceinline__ unsigned umin_dpp(unsigned x) {
    unsigned o = (unsigned)__builtin_amdgcn_update_dpp((int)x, (int)x, CTRL,
                                                       0xf, 0xf, false);
    return o < x ? o : x;
}

// full-wave unsigned-min; result valid in lane 63 only.
__device__ __forceinline__ unsigned wave_min_to_lane63(unsigned x) {
    x = umin_dpp<0x111>(x);   // row_shr:1
    x = umin_dpp<0x112>(x);   // row_shr:2
    x = umin_dpp<0x114>(x);   // row_shr:4
    x = umin_dpp<0x118>(x);   // row_shr:8  -> lane15 of each 16-row
    x = umin_dpp<0x142>(x);   // row_bcast:15 -> lane31/lane63 combine pairs
    x = umin_dpp<0x143>(x);   // row_bcast:31 -> lane63 = wave min
    return x;
}

__device__ __forceinline__ unsigned umin3(unsigned a, unsigned b, unsigned c) {
    unsigned t = a < b ? a : b;          // fuses to v_min3_u32
    return t < c ? t : c;
}

// biased key: coords pre-shifted <<5 so sdot2 gives d2<<10; acc = idx-1024
__device__ __forceinline__ unsigned mk_key(unsigned ps, unsigned qs, int izb) {
#if __has_builtin(__builtin_amdgcn_sdot2)
    v2s d = __builtin_bit_cast(v2s, ps) - __builtin_bit_cast(v2s, qs);
    return (unsigned)__builtin_amdgcn_sdot2(d, d, izb, false);
#else
    int dr = (int)(short)(ps >> 16) - (int)(short)(qs >> 16);
    int dc = (int)(short)(ps & 0xFFFFu) - (int)(short)(qs & 0xFFFFu);
    return (unsigned)(dr * dr + dc * dc + izb);
#endif
}

// own-slot (partitioned) init/update: global slot index = wid*4 + sl
#define OSLOT_INIT(sl)                                                    \
    oi##sl = (((wid * 4 + sl) << 6) | lane) - 1024;  /* idx - 1024 */     \
    oq##sl = base[((wid * 4 + sl) << 6) | lane] << 5;                     \
    ok##sl = mk_key(oq##sl, pt0s, oi##sl);   /* node0 self-kills */

#define OSLOT_UPD(sl)                                                     \
    { unsigned _nk = mk_key(oq##sl, pjs, oi##sl);                         \
      ok##sl = (unsigned)min((int)ok##sl, (int)_nk); }  /* signed: dead wins */

#define SEL16P(res)                                                       \
    { unsigned _a0 = b0 ? p1  : p0;                                       \
      unsigned _a1 = b0 ? p3  : p2;                                       \
      unsigned _a2 = b0 ? p5  : p4;                                       \
      unsigned _a3 = b0 ? p7  : p6;                                       \
      unsigned _a4 = b0 ? p9  : p8;                                       \
      unsigned _a5 = b0 ? p11 : p10;                                      \
      unsigned _a6 = b0 ? p13 : p12;                                      \
      unsigned _a7 = b0 ? p15 : p14;                                      \
      unsigned _c0 = b1 ? _a1 : _a0;                                      \
      unsigned _c1 = b1 ? _a3 : _a2;                                      \
      unsigned _c2 = b1 ? _a5 : _a4;                                      \
      unsigned _c3 = b1 ? _a7 : _a6;                                      \
      unsigned _e0 = b2 ? _c1 : _c0;                                      \
      unsigned _e1 = b2 ? _c3 : _c2;                                      \
      res = b3 ? _e1 : _e0; }

__global__ __launch_bounds__(256, 1) void mst_kernel(const unsigned* __restrict__ ptsG,
                                                     unsigned* __restrict__ edgesG) {
    __shared__ __align__(16) unsigned xmin[2][4];   // parity double-buffer
    int tid = threadIdx.x;
    int lane = tid & 63, wid = tid >> 6;
    int m = blockIdx.x;
    const unsigned* base = ptsG + m * KPTS;
    unsigned pt0s = base[0] << 5;    // self point 0, shifted (uniform)

    // replicated full point set (read-only; feeds SEL16P in every wave)
    unsigned p0  = base[( 0 << 6) | lane] << 5;
    unsigned p1  = base[( 1 << 6) | lane] << 5;
    unsigned p2  = base[( 2 << 6) | lane] << 5;
    unsigned p3  = base[( 3 << 6) | lane] << 5;
    unsigned p4  = base[( 4 << 6) | lane] << 5;
    unsigned p5  = base[( 5 << 6) | lane] << 5;
    unsigned p6  = base[( 6 << 6) | lane] << 5;
    unsigned p7  = base[( 7 << 6) | lane] << 5;
    unsigned p8  = base[( 8 << 6) | lane] << 5;
    unsigned p9  = base[( 9 << 6) | lane] << 5;
    unsigned p10 = base[(10 << 6) | lane] << 5;
    unsigned p11 = base[(11 << 6) | lane] << 5;
    unsigned p12 = base[(12 << 6) | lane] << 5;
    unsigned p13 = base[(13 << 6) | lane] << 5;
    unsigned p14 = base[(14 << 6) | lane] << 5;
    unsigned p15 = base[(15 << 6) | lane] << 5;

    // this wave's 4 owned key slots
    unsigned oq0, oq1, oq2, oq3;
    unsigned ok0, ok1, ok2, ok3;
    int      oi0, oi1, oi2, oi3;
    OSLOT_INIT(0); OSLOT_INIT(1); OSLOT_INIT(2); OSLOT_INIT(3);

    unsigned* eout = edgesG + m * KPTS;
    unsigned r3i = umin3(ok0, ok1, ok2);
    unsigned rk = r3i < ok3 ? r3i : ok3;    // per-lane min over own 4 slots

    unsigned acc = 0;                // per-lane edge accumulator (batch of 64)
    int par = 0;

    for (int chk = 0; chk < 16; chk++) {
        int tmax = (chk < 15) ? 64 : 63;     // 15*64 + 63 = 1023 iterations
        for (int t = 0; t < tmax; t++) {
            // ---- per-wave reduce (6 DPP mins, result in lane63) ----
            unsigned wmin = wave_min_to_lane63(rk);
            if (lane == 63) xmin[par][wid] = wmin;
            __syncthreads();

            // ---- cross-wave combine: broadcast b128 read of 4 minima ----
            u32x4 xv = *reinterpret_cast<const u32x4*>(&xmin[par][0]);
            unsigned vm = umin3(xv.x, xv.y, xv.z);
            vm = vm < xv.w ? vm : xv.w;
            unsigned wk = (unsigned)__builtin_amdgcn_readfirstlane((int)vm) + 1024u;
            par ^= 1;

            unsigned j = wk & 1023u;
            int wslot = (int)(j >> 6);
            int wlane = (int)(j & 63u);

            // ---- pj (shifted coords) from replicated regs: SEL16+readlane --
            bool b0 = (wslot & 1) != 0, b1 = (wslot & 2) != 0;
            bool b2 = (wslot & 4) != 0, b3 = (wslot & 8) != 0;
            unsigned selPay;
            SEL16P(selPay);
            unsigned pjs = (unsigned)__builtin_amdgcn_readlane((int)selPay, wlane);

            // ---- edge record: cndmask accumulate into lane t ----
            acc = (lane == t) ? wk : acc;

            // ---- decrease-key on own 4 slots; extracted slot self-kills ----
            OSLOT_UPD(0); OSLOT_UPD(1); OSLOT_UPD(2); OSLOT_UPD(3);
            unsigned r3 = umin3(ok0, ok1, ok2);
            rk = r3 < ok3 ? r3 : ok3;       // next iteration's per-lane min
        }
        // wave 0 does the full-wave coalesced batch store; chk=15 lane63
        // writes eout[1023] (stale) which is never read by recover_kernel.
        if (wid == 0) eout[(chk << 6) + lane] = acc;
    }
}

// ---------------------------------------------------------------------------
// Kernel 4 (phase 2): recover src per edge + per-edge (Dp-Dm)^2.
// src[j] = earliest-extracted v with d2(v,j)==d2p (exact-int match) —
// provably identical to the reference's strict-'<' update history.
// ---------------------------------------------------------------------------
__global__ void recover_kernel(const unsigned* __restrict__ ptsG,
                               const unsigned* __restrict__ edgesG,
                               float* __restrict__ contrib) {
    __shared__ unsigned sS[KPTS];
    __shared__ unsigned sO[KPTS];
    __shared__ unsigned short sT[KPTS];   // extraction time + 1 (0 = root)
    int g = blockIdx.x, m = blockIdx.y;
    int tid = threadIdx.x;
    int partner = m ^ 1;

    for (int i = tid; i < KPTS; i += 256) {
        sS[i] = ptsG[m * KPTS + i];
        sO[i] = ptsG[partner * KPTS + i];
    }
    for (int e = tid; e < KPTS - 1; e += 256) {
        unsigned wkk = edgesG[m * KPTS + e];
        sT[wkk & 1023u] = (unsigned short)(e + 1);
    }
    if (tid == 0) sT[0] = 0;
    __syncthreads();

    int lane = tid & 63, w = tid >> 6;
    for (int k = 0; k < 16; k++) {
        int e = g * 64 + w * 16 + k;
        if (e >= KPTS - 1) break;            // only e=1023 (g=15,w=3,k=15)
        unsigned wk = edgesG[m * KPTS + e];
        unsigned j = wk & 1023u;
        unsigned d2p = wk >> 10;
        unsigned pj = sS[j];
        unsigned te1 = (unsigned)(e + 1);

        unsigned best = 0xFFFFFFFFu;
#pragma unroll
        for (int i = 0; i < 16; i++) {
            int v = i * 64 + lane;
            unsigned pv = sS[v];
            int d2 = dist2_packed(pv, pj);
            unsigned tv1 = (unsigned)sT[v];
            bool qual = ((unsigned)d2 == d2p) && (tv1 < te1);
            unsigned cand = qual ? ((tv1 << 10) | (unsigned)v) : 0xFFFFFFFFu;
            best = cand < best ? cand : best;
        }
#pragma unroll
        for (int dd = 32; dd; dd >>= 1) {
            unsigned o = (unsigned)__shfl_xor((int)best, dd, 64);
            best = o < best ? o : best;
        }
        unsigned vsrc = best & 1023u;
        if (lane == 0) {
            unsigned oj = sO[j], os = sO[vsrc];
            float Dp = __fsqrt_rn((float)d2p);
            float Dm = __fsqrt_rn((float)dist2_packed(oj, os));
            float diff = Dp - Dm;
            contrib[m * (KPTS - 1) + e] = diff * diff;
        }
    }
}

// ---------------------------------------------------------------------------
// Kernel 5: per-image f64 sum (extraction order, deterministic) -> loss
// ---------------------------------------------------------------------------
__global__ void final_kernel(const float* __restrict__ contrib,
                             float* __restrict__ out) {
    __shared__ double part[NIMG];
    int t = threadIdx.x;
    if (t < NIMG) {
        double s = 0.0;
        for (int e = 0; e < KPTS - 1; e++)
            s += (double)contrib[t * (KPTS - 1) + e];
        part[t] = sqrt(s);
    }
    __syncthreads();
    if (t == 0) {
        double tot = 0.0;
        for (int i = 0; i < NIMG; i++) tot += part[i];
        out[0] = (float)(0.1 * tot / 8.0);
    }
}

// ---------------------------------------------------------------------------
// ws layout:
//   [0,512K)     maskbits (lbp->select), then DEAD:
//   [0,64K)      edgesG   (mst->recover)   — overlaps dead maskbits
//   [64K,128K)   contrib  (recover->final) — overlaps dead maskbits
//   [512K,576K)  ptsG     (select->mst/recover)
// ---------------------------------------------------------------------------
extern "C" void kernel_launch(void* const* d_in, const int* in_sizes, int n_in,
                              void* d_out, int out_size, void* d_ws, size_t ws_size,
                              hipStream_t stream) {
    const float* mo = (const float*)d_in[1];   // model_output
    const float* lb = (const float*)d_in[2];   // labels

    unsigned long long* maskbits = (unsigned long long*)d_ws;
    unsigned* edgesG = (unsigned*)d_ws;
    float* contrib = (float*)((char*)d_ws + (size_t)64 * 1024);
    unsigned* ptsG = (unsigned*)((char*)d_ws + (size_t)NIMG * NWORDS * 8);
    float* out = (float*)d_out;

    lbp_kernel<<<dim3(NPIX / 256, NIMG), 256, 0, stream>>>(mo, lb, maskbits);
    select_kernel<<<NIMG, 256, 0, stream>>>(maskbits, ptsG);
    mst_kernel<<<NIMG, 256, 0, stream>>>(ptsG, edgesG);
    recover_kernel<<<dim3(16, NIMG), 256, 0, stream>>>(ptsG, edgesG, contrib);
    final_kernel<<<1, 64, 0, stream>>>(contrib, out);
}